// Round 6
// baseline (291.418 us; speedup 1.0000x reference)
//
#include <hip/hip_runtime.h>
#include <hip/hip_bf16.h>

using bf16 = __hip_bfloat16;
using bf16x8 = __attribute__((ext_vector_type(8))) short;   // 8 bf16 = 4 VGPRs (MFMA A/B frag)
using f32x4  = __attribute__((ext_vector_type(4))) float;   // MFMA C/D frag (native vector)

#define B_    16
#define HIM   56
#define WIM   56
#define HD    512
#define NHEAD 8
#define DH    64
#define NTOK  (HIM*WIM)      // 3136
#define M_    (B_*NTOK)      // 50176
#define K49   49

// ---- async global->LDS, 16B per lane; LDS dest = wave-uniform base (+lane*16 by HW) ----
__device__ __forceinline__ void gload_lds16(const void* g, void* l) {
  __builtin_amdgcn_global_load_lds(
      (__attribute__((address_space(1))) const void*)g,
      (__attribute__((address_space(3))) void*)l, 16, 0, 0);
}

// ---------------- kernel: fp32 -> bf16 convert (vectorized, 8 elems/thread) ----------------
__global__ __launch_bounds__(256) void cvt_x_kernel(const float* __restrict__ in,
                                                    bf16* __restrict__ out) {
  size_t i = ((size_t)blockIdx.x * 256 + threadIdx.x) * 8;
  float4 a = *(const float4*)(in + i);
  float4 b = *(const float4*)(in + i + 4);
  union { uint4 v; bf16 h[8]; } o;
  o.h[0] = __float2bfloat16(a.x); o.h[1] = __float2bfloat16(a.y);
  o.h[2] = __float2bfloat16(a.z); o.h[3] = __float2bfloat16(a.w);
  o.h[4] = __float2bfloat16(b.x); o.h[5] = __float2bfloat16(b.y);
  o.h[6] = __float2bfloat16(b.z); o.h[7] = __float2bfloat16(b.w);
  *(uint4*)(out + i) = o.v;
}

// ---------------- kernel: W (K x N) -> Wt (N x K) bf16 ----------------
__global__ __launch_bounds__(256) void cvt_transpose_kernel(const float* __restrict__ in,
                                                            bf16* __restrict__ out,
                                                            int K, int N) {
  int idx = blockIdx.x * 256 + threadIdx.x;   // grid covers K*N exactly
  int k = idx / N, n = idx - k * N;
  out[(size_t)n * K + k] = __float2bfloat16(in[idx]);
}

// ============================================================================
// 256x256-tile GEMM, 1024 threads = 16 waves (4M x 4N, wave tile 64x64).
// 4 waves/SIMD (vs round-5's 2): barrier/vmcnt/ds-latency bubbles of one wave
// overlap MFMA of the other 3 (m114 mechanism) — round 5's 34%-util convoy.
// BK=32, 4-slot LDS ring (128 KiB), counted vmcnt(4): stage(j+3) issued after
// top-of-j barrier (overwrites slot last read at j-1); per-wave vmcnt before
// the barrier proves kslice-j loads landed. 1 gload_lds per thread per half.
// XOR swizzle slot^((row>>1)&3): pre-swizzled global src, linear LDS dest,
// same involution on ds_read (rounds 1-5: SQ_LDS_BANK_CONFLICT == 0).
// mfma(b,a) operand swap: lane holds 4 consecutive C-cols of one row ->
// packed 8B/16B epilogue stores (round 4-5: WRITE == ideal).
// ============================================================================
template<int N, bool OUT_BF16, bool BIAS>
__global__ __launch_bounds__(1024, 4) void gemm256b_kernel(
    const bf16* __restrict__ A,    // M x 512 row-major
    const bf16* __restrict__ Bt,   // N x 512 row-major
    void* __restrict__ Cp,
    const float* __restrict__ bias,
    int NBX)
{
  constexpr int K  = 512;
  constexpr int NK = K / 32;       // 16 kslices
  __shared__ alignas(16) bf16 lds[2][4][256 * 32];   // [A/B][slot][row*32+col] = 128 KiB
  const int tid  = threadIdx.x;
  const int lane = tid & 63, wid = tid >> 6;          // 16 waves
  const int l15  = lane & 15, kq = lane >> 4;
  const int wm   = wid >> 2,  wn = wid & 3;           // 4x4 wave grid
  // XCD-aware swizzle (gridDim.x % 8 == 0 for both launches)
  const int cpx = gridDim.x >> 3;
  const int wg  = (blockIdx.x & 7) * cpx + (blockIdx.x >> 3);
  const int by  = wg / NBX, bx = wg - by * NBX;
  const long arow0 = (long)by * 256;
  const long bcol0 = (long)bx * 256;

  // stage one half (A or B of kslice j): 256 rows x 32 cols = 16 KB, 1 load/thread
  auto stageHalf = [&](int ab, int j) {
    const bf16* g = (ab ? Bt + bcol0 * K : A + arow0 * K) + j * 32;
    int row = tid >> 2, sl = tid & 3;
    int gs  = sl ^ ((row >> 1) & 3);  // pre-swizzled global source slot
    gload_lds16((const char*)(g + (long)row * K) + gs * 16,
                &lds[ab][j & 3][wid * 64 * 8]);   // wave-uniform dest, +lane*16 by HW
  };

  f32x4 acc[4][4] = {};   // [mt][nt]: C rows wm*64+mt*16+l15, cols wn*64+nt*16+kq*4+r

#define KSLICE(SL, VMSTR, DOSTAGE, JSTAGE) {                                            \
    asm volatile("s_waitcnt vmcnt(" VMSTR ")" ::: "memory");                            \
    __builtin_amdgcn_s_barrier();                                                       \
    if (DOSTAGE) { stageHalf(0, JSTAGE); stageHalf(1, JSTAGE); }                        \
    bf16x8 bb[4];                                                                       \
    _Pragma("unroll")                                                                   \
    for (int nt = 0; nt < 4; ++nt) {                                                    \
      int row = wn * 64 + nt * 16 + l15;                                                \
      bb[nt] = *(const bf16x8*)&lds[1][SL][row * 32 + ((kq ^ ((row >> 1) & 3)) << 3)];  \
    }                                                                                   \
    __builtin_amdgcn_s_setprio(1);                                                      \
    _Pragma("unroll")                                                                   \
    for (int mt = 0; mt < 4; ++mt) {                                                    \
      int row = wm * 64 + mt * 16 + l15;                                                \
      bf16x8 af = *(const bf16x8*)&lds[0][SL][row * 32 + ((kq ^ ((row >> 1) & 3)) << 3)];\
      _Pragma("unroll")                                                                 \
      for (int nt = 0; nt < 4; ++nt)                                                    \
        acc[mt][nt] = __builtin_amdgcn_mfma_f32_16x16x32_bf16(bb[nt], af,               \
                                                              acc[mt][nt], 0, 0, 0);    \
    }                                                                                   \
    __builtin_amdgcn_s_setprio(0);                                                      \
  }

  // prologue: 3 kslices in flight (6 loads/wave)
  stageHalf(0, 0); stageHalf(1, 0);
  stageHalf(0, 1); stageHalf(1, 1);
  stageHalf(0, 2); stageHalf(1, 2);

  // steady state: kslices 0..11 (slot compile-time via unroll-4 groups)
#pragma unroll 1
  for (int jo = 0; jo < NK - 4; jo += 4) {
    KSLICE(0, "4", true, jo + 3);
    KSLICE(1, "4", true, jo + 4);
    KSLICE(2, "4", true, jo + 5);
    KSLICE(3, "4", true, jo + 6);
  }
  // tail: j = 12 (stages 15), 13, 14, 15
  KSLICE(0, "4", true,  15);
  KSLICE(1, "4", false, 0);
  KSLICE(2, "2", false, 0);
  KSLICE(3, "0", false, 0);
#undef KSLICE

  // epilogue: lane holds rows crow0+mt*16+l15, cols ccol0+nt*16+kq*4+{0..3}
  const long crow0 = arow0 + wm * 64;
  const long ccol0 = bcol0 + wn * 64 + kq * 4;
#pragma unroll
  for (int mt = 0; mt < 4; ++mt) {
    long row = crow0 + mt * 16 + l15;
#pragma unroll
    for (int nt = 0; nt < 4; ++nt) {
      long col = ccol0 + nt * 16;
      if (OUT_BF16) {
        union { unsigned long long u; unsigned short h[4]; } pk;
#pragma unroll
        for (int r = 0; r < 4; ++r) {
          bf16 hh = __float2bfloat16(acc[mt][nt][r]);
          pk.h[r] = *(unsigned short*)&hh;
        }
        __builtin_nontemporal_store(pk.u,
            (unsigned long long*)((bf16*)Cp + row * N + col));
      } else {
        f32x4 o = acc[mt][nt];
        if (BIAS) {
          o[0] += bias[col];     o[1] += bias[col + 1];
          o[2] += bias[col + 2]; o[3] += bias[col + 3];
        }
        __builtin_nontemporal_store(o, (f32x4*)((float*)Cp + row * N + col));
      }
    }
  }
}

// ============================================================================
// Windowed attention v2: ONE block per (b, window); 512 threads, wave g = head g.
// All loads are full 1-KB coalesced wave-rows (vs round-5's 16B granules x8192
// tiny blocks). LDS: KsR [64][528] (stride 528 -> b128 reads 2-way free),
// Vt [512][72] (V transposed on stage; lane-rotate cuts write conflicts to
// 8-way). Q staged into KsR, frags pulled to regs, K restaged over it; P
// overwrites wave g's own K-slice (wave-private cols, same-wave DS ordering).
// ============================================================================
__global__ __launch_bounds__(512) void attn_win2_kernel(
    const bf16* __restrict__ qkv, const float* __restrict__ rb, bf16* __restrict__ outa)
{
  __shared__ alignas(16) bf16 KsR[64 * 528];   // 67,584 B
  __shared__ alignas(16) bf16 Vt[512 * 72];    // 73,728 B
  const int tid = threadIdx.x, lane = tid & 63, wid = tid >> 6;
  const int p = blockIdx.x, b = blockIdx.y;
  const int sh = p >> 3, sw = p & 7;
  const size_t nb = (size_t)b * NTOK;
  const int l15 = lane & 15, kq = lane >> 4;
  const int g = wid;                           // head = wave

  // token t (0..48) -> global token index
  auto nOf = [&](int t) { int ph = t / 7, pw = t - ph * 7;
                          return (sh * 7 + ph) * WIM + sw * 7 + pw; };

  // ---- stage Q rows (into KsR) + V transposed (into Vt); zero pad t>=49 ----
  unsigned short* vt16 = (unsigned short*)Vt;
#pragma unroll
  for (int it = 0; it < 8; ++it) {
    int t = it * 8 + wid;
    int ch = lane * 8;
    uint4 vq = {0, 0, 0, 0}, vv = vq;
    if (t < K49) {
      const bf16* src = qkv + (nb + nOf(t)) * 1536 + ch;
      vq = *(const uint4*)(src);           // q cols 0..511
      vv = *(const uint4*)(src + 1024);    // v cols 1024..1535
    }
    *(uint4*)&KsR[t * 528 + ch] = vq;
    union { uint4 u; unsigned short s[8]; } uv; uv.u = vv;
#pragma unroll
    for (int i = 0; i < 8; ++i) {
      int e = (i + lane) & 7;              // rotate: 64-way -> 8-way bank conflict
      vt16[(ch + e) * 72 + t] = uv.s[e];
    }
  }
  __syncthreads();

  // ---- pull Q-frags for head g into registers ----
  bf16x8 aq[4][2];
#pragma unroll
  for (int mt = 0; mt < 4; ++mt)
#pragma unroll
    for (int kk = 0; kk < 2; ++kk)
      aq[mt][kk] = *(const bf16x8*)&KsR[(mt * 16 + l15) * 528 + g * 64 + kk * 32 + kq * 8];
  __syncthreads();   // all waves' Q reads done before K overwrites

  // ---- restage K over KsR ----
#pragma unroll
  for (int it = 0; it < 8; ++it) {
    int t = it * 8 + wid;
    int ch = lane * 8;
    uint4 vk = {0, 0, 0, 0};
    if (t < K49) vk = *(const uint4*)(qkv + (nb + nOf(t)) * 1536 + 512 + ch);
    *(uint4*)&KsR[t * 528 + ch] = vk;
  }
  __syncthreads();

  // ---- S = Q K^T : per wave 64x64, S[q=mt*16+kq*4+r][k=ct*16+l15] ----
  bf16x8 bk[4][2];
#pragma unroll
  for (int ct = 0; ct < 4; ++ct)
#pragma unroll
    for (int kk = 0; kk < 2; ++kk)
      bk[ct][kk] = *(const bf16x8*)&KsR[(ct * 16 + l15) * 528 + g * 64 + kk * 32 + kq * 8];
  f32x4 accS[4][4] = {};
#pragma unroll
  for (int mt = 0; mt < 4; ++mt)
#pragma unroll
    for (int ct = 0; ct < 4; ++ct)
#pragma unroll
      for (int kk = 0; kk < 2; ++kk)
        accS[mt][ct] = __builtin_amdgcn_mfma_f32_16x16x32_bf16(aq[mt][kk], bk[ct][kk],
                                                               accS[mt][ct], 0, 0, 0);
  // ---- bias + scale + pad-key mask ----
#pragma unroll
  for (int mt = 0; mt < 4; ++mt)
#pragma unroll
    for (int ct = 0; ct < 4; ++ct) {
      int kcol = ct * 16 + l15;
#pragma unroll
      for (int r = 0; r < 4; ++r) {
        int q = mt * 16 + kq * 4 + r;
        float x = accS[mt][ct][r];
        if (q < K49 && kcol < K49) x += rb[((size_t)g * K49 + q) * K49 + kcol];
        x *= 0.125f;
        accS[mt][ct][r] = (kcol < K49) ? x : -1e30f;
      }
    }
  // ---- softmax over k (4 in-lane + 16-lane shfl) ; P -> wave g's K-slice ----
#pragma unroll
  for (int mt = 0; mt < 4; ++mt)
#pragma unroll
    for (int r = 0; r < 4; ++r) {
      float m = fmaxf(fmaxf(accS[mt][0][r], accS[mt][1][r]),
                      fmaxf(accS[mt][2][r], accS[mt][3][r]));
#pragma unroll
      for (int d = 1; d < 16; d <<= 1) m = fmaxf(m, __shfl_xor(m, d));
      float e0 = __expf(accS[mt][0][r] - m), e1 = __expf(accS[mt][1][r] - m);
      float e2 = __expf(accS[mt][2][r] - m), e3 = __expf(accS[mt][3][r] - m);
      float s = e0 + e1 + e2 + e3;
#pragma unroll
      for (int d = 1; d < 16; d <<= 1) s += __shfl_xor(s, d);
      float inv = 1.0f / s;
      int q = mt * 16 + kq * 4 + r;
      bf16* pd = &KsR[q * 528 + g * 64 + l15];
      pd[ 0] = __float2bfloat16(e0 * inv);
      pd[16] = __float2bfloat16(e1 * inv);
      pd[32] = __float2bfloat16(e2 * inv);
      pd[48] = __float2bfloat16(e3 * inv);
    }

  // ---- O = P V (same-wave DS ordering: reads see this wave's P writes) ----
  bf16x8 ap[4][2], bv[4][2];
#pragma unroll
  for (int mt = 0; mt < 4; ++mt)
#pragma unroll
    for (int kk = 0; kk < 2; ++kk)
      ap[mt][kk] = *(const bf16x8*)&KsR[(mt * 16 + l15) * 528 + g * 64 + kk * 32 + kq * 8];
#pragma unroll
  for (int ct = 0; ct < 4; ++ct)
#pragma unroll
    for (int kk = 0; kk < 2; ++kk)
      bv[ct][kk] = *(const bf16x8*)&Vt[(g * 64 + ct * 16 + l15) * 72 + kk * 32 + kq * 8];
  f32x4 accO[4][4] = {};
#pragma unroll
  for (int mt = 0; mt < 4; ++mt)
#pragma unroll
    for (int ct = 0; ct < 4; ++ct)
#pragma unroll
      for (int kk = 0; kk < 2; ++kk)
        accO[mt][ct] = __builtin_amdgcn_mfma_f32_16x16x32_bf16(ap[mt][kk], bv[ct][kk],
                                                               accO[mt][ct], 0, 0, 0);
  // ---- store O[q][g*64 + ct*16 + l15] for q < 49 ----
#pragma unroll
  for (int mt = 0; mt < 4; ++mt)
#pragma unroll
    for (int r = 0; r < 4; ++r) {
      int q = mt * 16 + kq * 4 + r;
      if (q < K49) {
        bf16* dst = outa + (nb + nOf(q)) * HD + g * 64 + l15;
#pragma unroll
        for (int ct = 0; ct < 4; ++ct)
          dst[ct * 16] = __float2bfloat16(accO[mt][ct][r]);
      }
    }
}

// ---------------- launch ----------------
extern "C" void kernel_launch(void* const* d_in, const int* in_sizes, int n_in,
                              void* d_out, int out_size, void* d_ws, size_t ws_size,
                              hipStream_t stream) {
  (void)in_sizes; (void)n_in; (void)out_size;
  const float* x     = (const float*)d_in[0];
  // d_in[1] = mask: all-False with zero padding (56 % 7 == 0) -> no-op, skipped
  const float* wqkv  = (const float*)d_in[2];
  const float* wproj = (const float*)d_in[3];
  const float* bproj = (const float*)d_in[4];
  const float* rb    = (const float*)d_in[5];
  // d_in[6], d_in[7] = H, W (56, 56) constants

  // workspace layout (207,618,048 bytes total)
  char* ws = (char*)d_ws;
  bf16* x_bf    = (bf16*)(ws);              // 51,380,224 B ; reused as attnout after GEMM1
  bf16* wqkv_t  = (bf16*)(ws + 51380224);   //  1,572,864 B
  bf16* wproj_t = (bf16*)(ws + 52953088);   //    524,288 B
  bf16* qkv     = (bf16*)(ws + 53477376);   // 154,140,672 B
  bf16* attno   = x_bf;
  float* out    = (float*)d_out;
  if (ws_size < 207618048) return;  // fail visibly rather than corrupt

  cvt_x_kernel<<<dim3(12544), 256, 0, stream>>>(x, x_bf);                       // 50176*512/8/256
  cvt_transpose_kernel<<<dim3(3072), 256, 0, stream>>>(wqkv, wqkv_t, 512, 1536);
  cvt_transpose_kernel<<<dim3(1024), 256, 0, stream>>>(wproj, wproj_t, 512, 512);
  // GEMM1: 196 M-tiles x 6 N-tiles = 1176 blocks (1176 % 8 == 0)
  gemm256b_kernel<1536, true, false><<<dim3(1176), 1024, 0, stream>>>(
      x_bf, wqkv_t, (void*)qkv, nullptr, 6);
  attn_win2_kernel<<<dim3(64, B_), 512, 0, stream>>>(qkv, rb, attno);
  // GEMM2: 196 x 2 = 392 blocks (392 % 8 == 0)
  gemm256b_kernel<512, false, true><<<dim3(392), 1024, 0, stream>>>(
      attno, wproj_t, (void*)out, bproj, 2);
}

// Round 7
// 265.900 us; speedup vs baseline: 1.0960x; 1.0960x over previous
//
#include <hip/hip_runtime.h>
#include <hip/hip_bf16.h>

using bf16 = __hip_bfloat16;
using bf16x8 = __attribute__((ext_vector_type(8))) short;   // 8 bf16 = 4 VGPRs (MFMA A/B frag)
using f32x4  = __attribute__((ext_vector_type(4))) float;   // MFMA C/D frag (native vector)

#define B_    16
#define HIM   56
#define WIM   56
#define HD    512
#define NHEAD 8
#define DH    64
#define NTOK  (HIM*WIM)      // 3136
#define M_    (B_*NTOK)      // 50176
#define K49   49

// ---- async global->LDS, 16B per lane; LDS dest = wave-uniform base (+lane*16 by HW) ----
__device__ __forceinline__ void gload_lds16(const void* g, void* l) {
  __builtin_amdgcn_global_load_lds(
      (__attribute__((address_space(1))) const void*)g,
      (__attribute__((address_space(3))) void*)l, 16, 0, 0);
}

// ---------------- kernel: fp32 -> bf16 convert (vectorized, 8 elems/thread) ----------------
__global__ __launch_bounds__(256) void cvt_x_kernel(const float* __restrict__ in,
                                                    bf16* __restrict__ out) {
  size_t i = ((size_t)blockIdx.x * 256 + threadIdx.x) * 8;
  float4 a = *(const float4*)(in + i);
  float4 b = *(const float4*)(in + i + 4);
  union { uint4 v; bf16 h[8]; } o;
  o.h[0] = __float2bfloat16(a.x); o.h[1] = __float2bfloat16(a.y);
  o.h[2] = __float2bfloat16(a.z); o.h[3] = __float2bfloat16(a.w);
  o.h[4] = __float2bfloat16(b.x); o.h[5] = __float2bfloat16(b.y);
  o.h[6] = __float2bfloat16(b.z); o.h[7] = __float2bfloat16(b.w);
  *(uint4*)(out + i) = o.v;
}

// ---------------- kernel: W (K x N) -> Wt (N x K) bf16 ----------------
__global__ __launch_bounds__(256) void cvt_transpose_kernel(const float* __restrict__ in,
                                                            bf16* __restrict__ out,
                                                            int K, int N) {
  int idx = blockIdx.x * 256 + threadIdx.x;   // grid covers K*N exactly
  int k = idx / N, n = idx - k * N;
  out[(size_t)n * K + k] = __float2bfloat16(in[idx]);
}

// ============================================================================
// PERSISTENT 256x256-tile GEMM: grid = 256 blocks (1/CU), each block owns a
// contiguous range of output tiles (runs of NBX share the A-panel -> L2 hot).
// 1024 threads = 16 waves (4Mx4N, wave tile 64x64). BK=32, 4-slot LDS ring
// (128 KiB), counted vmcnt that CONTINUES ACROSS TILE BOUNDARIES: stage(s+3)
// prefetches the next tile's first kslices during the current tile's last
// ones, and the epilogue's 16 NT stores (which enter the vmcnt FIFO) overlap
// the next tile's K-loop. vmcnt bookkeeping: j<3 of non-first tiles use
// vmcnt(20) (16 stores + 4 newer loads in FIFO ahead of the confirmed one);
// j>=3 use vmcnt(4); final tile tails ...,4,2,0.
// XOR swizzle slot^((row>>1)&3): pre-swizzled global src, linear LDS dest,
// same involution on ds_read (rounds 1-6: SQ_LDS_BANK_CONFLICT == 0).
// mfma(b,a) operand swap -> packed 8B/16B epilogue stores (WRITE == ideal).
// BIAS folded into acc-init (vb preloaded BEFORE the pipeline so no epilogue
// bias loads disturb the vmcnt count).
// ============================================================================
template<int N, bool OUT_BF16, bool BIAS>
__global__ __launch_bounds__(1024, 4) void gemm_persist_kernel(
    const bf16* __restrict__ A,    // M x 512 row-major
    const bf16* __restrict__ Bt,   // N x 512 row-major
    void* __restrict__ Cp,
    const float* __restrict__ bias,
    int NBX, int NTILES)
{
  constexpr int K = 512;
  __shared__ alignas(16) bf16 lds[2][4][256 * 32];   // [A/B][slot][row*32+col] = 128 KiB
  const int tid  = threadIdx.x;
  const int lane = tid & 63, wid = tid >> 6;          // 16 waves
  const int l15  = lane & 15, kq = lane >> 4;
  const int wm   = wid >> 2,  wn = wid & 3;           // 4x4 wave grid

  // contiguous tile range for this block
  const int bid  = blockIdx.x, nb = gridDim.x;
  int cnt = NTILES / nb;
  const int rem = NTILES - cnt * nb;
  const int tstart = bid * cnt + (bid < rem ? bid : rem);
  if (bid < rem) ++cnt;
  const int smax = cnt * 16;       // total kslice steps

  // bias preload into regs BEFORE any pipeline loads (only used when BIAS; NBX==2 there)
  f32x4 vb[2][4];
  if (BIAS) {
#pragma unroll
    for (int x = 0; x < 2; ++x)
#pragma unroll
      for (int nt = 0; nt < 4; ++nt)
        vb[x][nt] = *(const f32x4*)&bias[x * 256 + wn * 64 + nt * 16 + kq * 4];
  }

  // stage both halves of kslice-step s (may belong to any tile in the range)
  auto stageS = [&](int s) {
    const int tt = tstart + (s >> 4);
    const int j  = s & 15;
    const int by = tt / NBX, bx = tt - by * NBX;
    const bf16* gA = A  + (long)by * 256 * K + j * 32;
    const bf16* gB = Bt + (long)bx * 256 * K + j * 32;
    const int row = tid >> 2, sl = tid & 3;
    const int gs  = sl ^ ((row >> 1) & 3);   // pre-swizzled global source slot
    gload_lds16((const char*)(gA + (long)row * K) + gs * 16, &lds[0][s & 3][wid * 64 * 8]);
    gload_lds16((const char*)(gB + (long)row * K) + gs * 16, &lds[1][s & 3][wid * 64 * 8]);
  };

  // prologue: 3 kslices in flight (6 loads/wave)
  stageS(0); stageS(1); stageS(2);

  int s = 0;
#pragma unroll 1
  for (int tl = 0; tl < cnt; ++tl) {
    f32x4 acc[4][4];
    const int tt = tstart + tl;
    const int bxt = tt - (tt / NBX) * NBX;
#pragma unroll
    for (int mt = 0; mt < 4; ++mt)
#pragma unroll
      for (int nt = 0; nt < 4; ++nt)
        acc[mt][nt] = BIAS ? vb[bxt][nt] : f32x4{0.f, 0.f, 0.f, 0.f};

#pragma unroll 1
    for (int j = 0; j < 16; ++j, ++s) {
      if (tl > 0 && j < 3)   asm volatile("s_waitcnt vmcnt(20)" ::: "memory");
      else if (s == smax - 2) asm volatile("s_waitcnt vmcnt(2)"  ::: "memory");
      else if (s == smax - 1) asm volatile("s_waitcnt vmcnt(0)"  ::: "memory");
      else                    asm volatile("s_waitcnt vmcnt(4)"  ::: "memory");
      __builtin_amdgcn_s_barrier();
      if (s + 3 < smax) stageS(s + 3);
      const int sl4 = s & 3;
      bf16x8 bb[4];
#pragma unroll
      for (int nt = 0; nt < 4; ++nt) {
        int row = wn * 64 + nt * 16 + l15;
        bb[nt] = *(const bf16x8*)&lds[1][sl4][row * 32 + ((kq ^ ((row >> 1) & 3)) << 3)];
      }
      __builtin_amdgcn_s_setprio(1);
#pragma unroll
      for (int mt = 0; mt < 4; ++mt) {
        int row = wm * 64 + mt * 16 + l15;
        bf16x8 af = *(const bf16x8*)&lds[0][sl4][row * 32 + ((kq ^ ((row >> 1) & 3)) << 3)];
#pragma unroll
        for (int nt = 0; nt < 4; ++nt)
          acc[mt][nt] = __builtin_amdgcn_mfma_f32_16x16x32_bf16(bb[nt], af, acc[mt][nt], 0, 0, 0);
      }
      __builtin_amdgcn_s_setprio(0);
    }

    // epilogue (exactly 16 vmem ops -> accounted by the vmcnt(20) window)
    const int byt = tt / NBX;
    const long crow0 = (long)byt * 256 + wm * 64;
    const long ccol0 = (long)bxt * 256 + wn * 64 + kq * 4;
#pragma unroll
    for (int mt = 0; mt < 4; ++mt) {
      long row = crow0 + mt * 16 + l15;
#pragma unroll
      for (int nt = 0; nt < 4; ++nt) {
        long col = ccol0 + nt * 16;
        if (OUT_BF16) {
          union { unsigned long long u; unsigned short h[4]; } pk;
#pragma unroll
          for (int r = 0; r < 4; ++r) {
            bf16 hh = __float2bfloat16(acc[mt][nt][r]);
            pk.h[r] = *(unsigned short*)&hh;
          }
          __builtin_nontemporal_store(pk.u,
              (unsigned long long*)((bf16*)Cp + row * N + col));
        } else {
          __builtin_nontemporal_store(acc[mt][nt], (f32x4*)((float*)Cp + row * N + col));
        }
      }
    }
  }
}

// ---------------- kernel: windowed attention, one WG per (b, window p, head g) ------------
// (round-5 v1, known-good) qkv: [B][3136][1536] bf16; rb: [8][49][49] fp32; outa bf16
__global__ __launch_bounds__(256) void attn_win_kernel(
    const bf16* __restrict__ qkv, const float* __restrict__ rb, bf16* __restrict__ outa)
{
  __shared__ alignas(16) bf16 Qs[64 * 72];  // [token][chan], stride 72 (144B -> 2-way free)
  __shared__ alignas(16) bf16 Ks[64 * 72];
  __shared__ alignas(16) bf16 Vt[64 * 72];  // transposed: [chan][token]
  __shared__ alignas(16) bf16 Ps[64 * 72];  // probabilities [q][k]
  const int tid = threadIdx.x, lane = tid & 63, wid = tid >> 6;
  const int p = blockIdx.x, g = blockIdx.y, b = blockIdx.z;
  const int sh = p >> 3, sw = p & 7;
  const size_t nb = (size_t)b * NTOK;
  const int c8 = (tid & 7) * 8;

  // stage Q,K row-major + V transposed; zero-fill pad tokens 49..63
#pragma unroll
  for (int it = 0; it < 2; ++it) {
    int t = (tid >> 3) + it * 32;
    uint4 vq = {0, 0, 0, 0}, vk = vq, vv = vq;
    if (t < K49) {
      int ph = t / 7, pw = t - ph * 7;
      int n = (sh * 7 + ph) * WIM + sw * 7 + pw;
      const bf16* src = qkv + (nb + n) * 1536 + g * 64 + c8;
      vq = *(const uint4*)(src);
      vk = *(const uint4*)(src + 512);
      vv = *(const uint4*)(src + 1024);
    }
    *(uint4*)&Qs[t * 72 + c8] = vq;
    *(uint4*)&Ks[t * 72 + c8] = vk;
    union { uint4 u; unsigned short s[8]; } uv; uv.u = vv;
    unsigned short* vt16 = (unsigned short*)Vt;
#pragma unroll
    for (int e = 0; e < 8; ++e) vt16[(c8 + e) * 72 + t] = uv.s[e];
  }
  __syncthreads();

  const int l15 = lane & 15, kq = lane >> 4;
  // ---- S = Q K^T (wave w owns q rows 16w..16w+15; 4 col tiles) ----
  bf16x8 aq[2];
#pragma unroll
  for (int kk = 0; kk < 2; ++kk)
    aq[kk] = *(const bf16x8*)&Qs[(wid * 16 + l15) * 72 + kk * 32 + kq * 8];
  float sv[4][4];   // [ct][r]
#pragma unroll
  for (int ct = 0; ct < 4; ++ct) {
    f32x4 acc = {0.f, 0.f, 0.f, 0.f};
#pragma unroll
    for (int kk = 0; kk < 2; ++kk) {
      bf16x8 bk = *(const bf16x8*)&Ks[(ct * 16 + l15) * 72 + kk * 32 + kq * 8];
      acc = __builtin_amdgcn_mfma_f32_16x16x32_bf16(aq[kk], bk, acc, 0, 0, 0);
    }
    int kcol = ct * 16 + l15;
#pragma unroll
    for (int r = 0; r < 4; ++r) {
      int q = wid * 16 + kq * 4 + r;
      float bias = (q < K49 && kcol < K49) ? rb[((size_t)g * K49 + q) * K49 + kcol] : 0.f;
      float v = (acc[r] + bias) * 0.125f;          // (S + rel_bias) * dh^-0.5
      sv[ct][r] = (kcol < K49) ? v : -1e30f;       // mask pad keys
    }
  }
  // ---- softmax over keys (row q lives in the 16 lanes sharing kq) ----
#pragma unroll
  for (int r = 0; r < 4; ++r) {
    float m = fmaxf(fmaxf(sv[0][r], sv[1][r]), fmaxf(sv[2][r], sv[3][r]));
#pragma unroll
    for (int d = 1; d < 16; d <<= 1) m = fmaxf(m, __shfl_xor(m, d));
    float e0 = __expf(sv[0][r] - m), e1 = __expf(sv[1][r] - m);
    float e2 = __expf(sv[2][r] - m), e3 = __expf(sv[3][r] - m);
    float s = e0 + e1 + e2 + e3;
#pragma unroll
    for (int d = 1; d < 16; d <<= 1) s += __shfl_xor(s, d);
    float inv = 1.0f / s;
    int q = wid * 16 + kq * 4 + r;
    Ps[q * 72 +  0 + l15] = __float2bfloat16(e0 * inv);
    Ps[q * 72 + 16 + l15] = __float2bfloat16(e1 * inv);
    Ps[q * 72 + 32 + l15] = __float2bfloat16(e2 * inv);
    Ps[q * 72 + 48 + l15] = __float2bfloat16(e3 * inv);
  }
  __syncthreads();
  // ---- O = P V ----
  bf16x8 ap[2];
#pragma unroll
  for (int kk = 0; kk < 2; ++kk)
    ap[kk] = *(const bf16x8*)&Ps[(wid * 16 + l15) * 72 + kk * 32 + kq * 8];
#pragma unroll
  for (int ct = 0; ct < 4; ++ct) {
    f32x4 acc = {0.f, 0.f, 0.f, 0.f};
#pragma unroll
    for (int kk = 0; kk < 2; ++kk) {
      bf16x8 bv = *(const bf16x8*)&Vt[(ct * 16 + l15) * 72 + kk * 32 + kq * 8];
      acc = __builtin_amdgcn_mfma_f32_16x16x32_bf16(ap[kk], bv, acc, 0, 0, 0);
    }
#pragma unroll
    for (int r = 0; r < 4; ++r) {
      int q = wid * 16 + kq * 4 + r;
      if (q < K49) {
        int ph = q / 7, pw = q - ph * 7;
        int n = (sh * 7 + ph) * WIM + sw * 7 + pw;
        outa[(nb + n) * HD + g * 64 + ct * 16 + l15] = __float2bfloat16(acc[r]);
      }
    }
  }
}

// ---------------- launch ----------------
extern "C" void kernel_launch(void* const* d_in, const int* in_sizes, int n_in,
                              void* d_out, int out_size, void* d_ws, size_t ws_size,
                              hipStream_t stream) {
  (void)in_sizes; (void)n_in; (void)out_size;
  const float* x     = (const float*)d_in[0];
  // d_in[1] = mask: all-False with zero padding (56 % 7 == 0) -> no-op, skipped
  const float* wqkv  = (const float*)d_in[2];
  const float* wproj = (const float*)d_in[3];
  const float* bproj = (const float*)d_in[4];
  const float* rb    = (const float*)d_in[5];
  // d_in[6], d_in[7] = H, W (56, 56) constants

  // workspace layout (207,618,048 bytes total)
  char* ws = (char*)d_ws;
  bf16* x_bf    = (bf16*)(ws);              // 51,380,224 B ; reused as attnout after GEMM1
  bf16* wqkv_t  = (bf16*)(ws + 51380224);   //  1,572,864 B
  bf16* wproj_t = (bf16*)(ws + 52953088);   //    524,288 B
  bf16* qkv     = (bf16*)(ws + 53477376);   // 154,140,672 B
  bf16* attno   = x_bf;
  float* out    = (float*)d_out;
  if (ws_size < 207618048) return;  // fail visibly rather than corrupt

  cvt_x_kernel<<<dim3(12544), 256, 0, stream>>>(x, x_bf);                       // 50176*512/8/256
  cvt_transpose_kernel<<<dim3(3072), 256, 0, stream>>>(wqkv, wqkv_t, 512, 1536);
  cvt_transpose_kernel<<<dim3(1024), 256, 0, stream>>>(wproj, wproj_t, 512, 512);
  // GEMM1: 196 M-tiles x 6 N-tiles = 1176 tiles, persistent over 256 blocks
  gemm_persist_kernel<1536, true, false><<<dim3(256), 1024, 0, stream>>>(
      x_bf, wqkv_t, (void*)qkv, nullptr, 6, 1176);
  attn_win_kernel<<<dim3(64, NHEAD, B_), 256, 0, stream>>>(qkv, rb, attno);
  // GEMM2: 196 x 2 = 392 tiles
  gemm_persist_kernel<512, false, true><<<dim3(256), 1024, 0, stream>>>(
      attno, wproj_t, (void*)out, bproj, 2, 392);
}

// Round 8
// 255.313 us; speedup vs baseline: 1.1414x; 1.0415x over previous
//
#include <hip/hip_runtime.h>
#include <hip/hip_bf16.h>

using bf16 = __hip_bfloat16;
using bf16x8 = __attribute__((ext_vector_type(8))) short;   // 8 bf16 = 4 VGPRs (MFMA A/B frag)
using f32x4  = __attribute__((ext_vector_type(4))) float;   // MFMA C/D frag (native vector)

#define B_    16
#define HIM   56
#define WIM   56
#define HD    512
#define NHEAD 8
#define DH    64
#define NTOK  (HIM*WIM)      // 3136
#define M_    (B_*NTOK)      // 50176
#define K49   49

// ---- async global->LDS, 16B per lane; LDS dest = wave-uniform base (+lane*16 by HW) ----
__device__ __forceinline__ void gload_lds16(const void* g, void* l) {
  __builtin_amdgcn_global_load_lds(
      (__attribute__((address_space(1))) const void*)g,
      (__attribute__((address_space(3))) void*)l, 16, 0, 0);
}

// ---------------- kernel: fp32 -> bf16 convert (vectorized, 8 elems/thread) ----------------
__global__ __launch_bounds__(256) void cvt_x_kernel(const float* __restrict__ in,
                                                    bf16* __restrict__ out) {
  size_t i = ((size_t)blockIdx.x * 256 + threadIdx.x) * 8;
  float4 a = *(const float4*)(in + i);
  float4 b = *(const float4*)(in + i + 4);
  union { uint4 v; bf16 h[8]; } o;
  o.h[0] = __float2bfloat16(a.x); o.h[1] = __float2bfloat16(a.y);
  o.h[2] = __float2bfloat16(a.z); o.h[3] = __float2bfloat16(a.w);
  o.h[4] = __float2bfloat16(b.x); o.h[5] = __float2bfloat16(b.y);
  o.h[6] = __float2bfloat16(b.z); o.h[7] = __float2bfloat16(b.w);
  *(uint4*)(out + i) = o.v;
}

// ---------------- kernel: W (K x N) -> Wt (N x K) bf16 ----------------
__global__ __launch_bounds__(256) void cvt_transpose_kernel(const float* __restrict__ in,
                                                            bf16* __restrict__ out,
                                                            int K, int N) {
  int idx = blockIdx.x * 256 + threadIdx.x;   // grid covers K*N exactly
  int k = idx / N, n = idx - k * N;
  out[(size_t)n * K + k] = __float2bfloat16(in[idx]);
}

// ============================================================================
// 256x256-tile GEMM with SHADOW-PHASED kslice loop.
// 512 threads = 8 waves (2M x 4N, wave tile 128x64). BK=32, 4-slot LDS ring.
// Per kslice j: { read af(j) x8 ; stage A(j+3) ; BARRIER ;
//                 16 MFMA (af x bf[0,1]) ; stage B(j+3) ;
//                 16 MFMA (af x bf[2,3]) ;
//                 PRE-READ bf(j+1) x4   <- in the barrier shadow: overlaps
//                 vmcnt(4) ; BARRIER }     other waves' MFMA tail
// B-frags double-buffered in registers (bfA/bfB by j parity) so each MFMA
// phase starts with B operands already resident; A-frags read at phase top.
// Gate algebra: end-of-(j-1) vmcnt(4) = all loads except {A(j+2),B(j+2)}
// landed => B(j+1) landed => tail pre-read of bf(j+1) and af(j+1) safe.
// Prologue vmcnt(4) proves A0,B0,A1,B1. Tail gates 4,0,0,0. Never a mid-loop
// drain-to-0 before the last 3 kslices.
// WAR on ring slot (j-1) (overwritten by stage(j+3)): last reads of slot j-1
// are af at P1(j-1) top and bf at tail of (j-2), both before end-of-(j-1)
// barrier, which precedes any wave's stage(j+3) issue. SAFE.
// XOR swizzle slot^((row>>1)&3) (rounds 1-7: SQ_LDS_BANK_CONFLICT == 0).
// mfma(b,a) operand swap -> packed 8B/16B epilogue NT stores (WRITE ideal).
// ============================================================================
template<int N, bool OUT_BF16, bool BIAS>
__global__ __launch_bounds__(512, 2) void gemm8p_kernel(
    const bf16* __restrict__ A,    // M x 512 row-major
    const bf16* __restrict__ Bt,   // N x 512 row-major
    void* __restrict__ Cp,
    const float* __restrict__ bias,
    int NBX)
{
  constexpr int K = 512;
  __shared__ alignas(16) bf16 lds[2][4][256 * 32];   // [A/B][slot][rr*32+col] = 128 KiB
  const int tid  = threadIdx.x;
  const int lane = tid & 63, wid = tid >> 6;          // 8 waves
  const int l15  = lane & 15, kq = lane >> 4;
  const int wm   = wid >> 2,  wn = wid & 3;           // 2M x 4N
  const int cpx = gridDim.x >> 3;                     // XCD swizzle (grid % 8 == 0)
  const int wg  = (blockIdx.x & 7) * cpx + (blockIdx.x >> 3);
  const int by  = wg / NBX, bx = wg - by * NBX;
  const long arow0 = (long)by * 256;
  const long bcol0 = (long)bx * 256;

  // stage half (A or B) of kslice j: 256x32 = 16KB, 2 gload_lds per thread
  auto stageHalf = [&](int ab, int j) {
    const bf16* g = (ab ? Bt + bcol0 * K : A + arow0 * K) + j * 32;
    bf16* lb = &lds[ab][j & 3][0];
#pragma unroll
    for (int c = 0; c < 2; ++c) {
      int s   = c * 512 + tid;
      int row = s >> 2, sl = s & 3;
      int gs  = sl ^ ((row >> 1) & 3);
      gload_lds16((const char*)(g + (long)row * K) + gs * 16,
                  lb + (c * 512 + wid * 64) * 8);
    }
  };
  auto rdA = [&](int slot, int mt) -> bf16x8 {
    int rr = wm * 128 + mt * 16 + l15;
    return *(const bf16x8*)&lds[0][slot][rr * 32 + ((kq ^ ((rr >> 1) & 3)) << 3)];
  };
  auto rdB = [&](int slot, int nt) -> bf16x8 {
    int rr = wn * 64 + nt * 16 + l15;
    return *(const bf16x8*)&lds[1][slot][rr * 32 + ((kq ^ ((rr >> 1) & 3)) << 3)];
  };

  f32x4 acc[8][4] = {};
  bf16x8 af[8], bfA[4], bfB[4];

  // prologue: stage kslices 0,1,2; prove {A0,B0,A1,B1}; pre-read bf(0)
  stageHalf(0, 0); stageHalf(1, 0);
  stageHalf(0, 1); stageHalf(1, 1);
  stageHalf(0, 2); stageHalf(1, 2);
  asm volatile("s_waitcnt vmcnt(4)" ::: "memory");
  __builtin_amdgcn_s_barrier();
#pragma unroll
  for (int nt = 0; nt < 4; ++nt) bfA[nt] = rdB(0, nt);

#define KS(SLOT, NSLOT, BFC, BFN, JST, DOST, PRE, VMSTR) {                    \
    _Pragma("unroll")                                                         \
    for (int mt = 0; mt < 8; ++mt) af[mt] = rdA(SLOT, mt);                    \
    if (DOST) stageHalf(0, JST);                                              \
    __builtin_amdgcn_s_barrier();                                             \
    __builtin_amdgcn_s_setprio(1);                                            \
    _Pragma("unroll")                                                         \
    for (int mt = 0; mt < 8; ++mt) {                                          \
      acc[mt][0] = __builtin_amdgcn_mfma_f32_16x16x32_bf16(BFC[0], af[mt],    \
                                                           acc[mt][0], 0,0,0);\
      acc[mt][1] = __builtin_amdgcn_mfma_f32_16x16x32_bf16(BFC[1], af[mt],    \
                                                           acc[mt][1], 0,0,0);\
    }                                                                         \
    __builtin_amdgcn_s_setprio(0);                                            \
    if (DOST) stageHalf(1, JST);                                              \
    __builtin_amdgcn_s_setprio(1);                                            \
    _Pragma("unroll")                                                         \
    for (int mt = 0; mt < 8; ++mt) {                                          \
      acc[mt][2] = __builtin_amdgcn_mfma_f32_16x16x32_bf16(BFC[2], af[mt],    \
                                                           acc[mt][2], 0,0,0);\
      acc[mt][3] = __builtin_amdgcn_mfma_f32_16x16x32_bf16(BFC[3], af[mt],    \
                                                           acc[mt][3], 0,0,0);\
    }                                                                         \
    __builtin_amdgcn_s_setprio(0);                                            \
    if (PRE) {                                                                \
      _Pragma("unroll")                                                       \
      for (int nt = 0; nt < 4; ++nt) BFN[nt] = rdB(NSLOT, nt);                \
    }                                                                         \
    asm volatile("s_waitcnt vmcnt(" VMSTR ")" ::: "memory");                  \
    __builtin_amdgcn_s_barrier();                                             \
  }

  // steady state: kslices 0..11 (slot/parity compile-time via unroll-4 group)
#pragma unroll 1
  for (int jo = 0; jo < 12; jo += 4) {
    KS(0, 1, bfA, bfB, jo + 3, 1, 1, "4");
    KS(1, 2, bfB, bfA, jo + 4, 1, 1, "4");
    KS(2, 3, bfA, bfB, jo + 5, 1, 1, "4");
    KS(3, 0, bfB, bfA, jo + 6, 1, 1, "4");
  }
  // tail: j = 12 (stages 15), 13, 14, 15
  KS(0, 1, bfA, bfB, 15, 1, 1, "4");
  KS(1, 2, bfB, bfA, 0,  0, 1, "0");
  KS(2, 3, bfA, bfB, 0,  0, 1, "0");
  KS(3, 0, bfB, bfA, 0,  0, 0, "0");
#undef KS

  // epilogue: lane holds rows crow0+mt*16+l15, cols ccol0+nt*16+kq*4+{0..3}
  const long crow0 = arow0 + wm * 128;
  const long ccol0 = bcol0 + wn * 64 + kq * 4;
#pragma unroll
  for (int mt = 0; mt < 8; ++mt) {
    long row = crow0 + mt * 16 + l15;
#pragma unroll
    for (int nt = 0; nt < 4; ++nt) {
      long col = ccol0 + nt * 16;
      if (OUT_BF16) {
        union { unsigned long long u; unsigned short h[4]; } pk;
#pragma unroll
        for (int r = 0; r < 4; ++r) {
          bf16 hh = __float2bfloat16(acc[mt][nt][r]);
          pk.h[r] = *(unsigned short*)&hh;
        }
        __builtin_nontemporal_store(pk.u,
            (unsigned long long*)((bf16*)Cp + row * N + col));
      } else {
        f32x4 o = acc[mt][nt];
        if (BIAS) {
          o[0] += bias[col];     o[1] += bias[col + 1];
          o[2] += bias[col + 2]; o[3] += bias[col + 3];
        }
        __builtin_nontemporal_store(o, (f32x4*)((float*)Cp + row * N + col));
      }
    }
  }
}

// ---------------- kernel: windowed attention, one WG per (b, window p, head g) ------------
// round-5 v1 + PV operand swap: mfma(bv, ap) -> lane holds 4 CONSECUTIVE output
// channels of one token (fragments are symmetric, identical LDS reads) ->
// 4 x 8B packed stores instead of 16 x 2B scatters.
__global__ __launch_bounds__(256) void attn_win_kernel(
    const bf16* __restrict__ qkv, const float* __restrict__ rb, bf16* __restrict__ outa)
{
  __shared__ alignas(16) bf16 Qs[64 * 72];  // [token][chan], stride 72 (144B -> 2-way free)
  __shared__ alignas(16) bf16 Ks[64 * 72];
  __shared__ alignas(16) bf16 Vt[64 * 72];  // transposed: [chan][token]
  __shared__ alignas(16) bf16 Ps[64 * 72];  // probabilities [q][k]
  const int tid = threadIdx.x, lane = tid & 63, wid = tid >> 6;
  const int p = blockIdx.x, g = blockIdx.y, b = blockIdx.z;
  const int sh = p >> 3, sw = p & 7;
  const size_t nb = (size_t)b * NTOK;
  const int c8 = (tid & 7) * 8;

  // stage Q,K row-major + V transposed; zero-fill pad tokens 49..63
#pragma unroll
  for (int it = 0; it < 2; ++it) {
    int t = (tid >> 3) + it * 32;
    uint4 vq = {0, 0, 0, 0}, vk = vq, vv = vq;
    if (t < K49) {
      int ph = t / 7, pw = t - ph * 7;
      int n = (sh * 7 + ph) * WIM + sw * 7 + pw;
      const bf16* src = qkv + (nb + n) * 1536 + g * 64 + c8;
      vq = *(const uint4*)(src);
      vk = *(const uint4*)(src + 512);
      vv = *(const uint4*)(src + 1024);
    }
    *(uint4*)&Qs[t * 72 + c8] = vq;
    *(uint4*)&Ks[t * 72 + c8] = vk;
    union { uint4 u; unsigned short s[8]; } uv; uv.u = vv;
    unsigned short* vt16 = (unsigned short*)Vt;
#pragma unroll
    for (int e = 0; e < 8; ++e) vt16[(c8 + e) * 72 + t] = uv.s[e];
  }
  __syncthreads();

  const int l15 = lane & 15, kq = lane >> 4;
  // ---- S = Q K^T (wave w owns q rows 16w..16w+15; 4 col tiles) ----
  bf16x8 aq[2];
#pragma unroll
  for (int kk = 0; kk < 2; ++kk)
    aq[kk] = *(const bf16x8*)&Qs[(wid * 16 + l15) * 72 + kk * 32 + kq * 8];
  float sv[4][4];   // [ct][r]
#pragma unroll
  for (int ct = 0; ct < 4; ++ct) {
    f32x4 acc = {0.f, 0.f, 0.f, 0.f};
#pragma unroll
    for (int kk = 0; kk < 2; ++kk) {
      bf16x8 bk = *(const bf16x8*)&Ks[(ct * 16 + l15) * 72 + kk * 32 + kq * 8];
      acc = __builtin_amdgcn_mfma_f32_16x16x32_bf16(aq[kk], bk, acc, 0, 0, 0);
    }
    int kcol = ct * 16 + l15;
#pragma unroll
    for (int r = 0; r < 4; ++r) {
      int q = wid * 16 + kq * 4 + r;
      float bias = (q < K49 && kcol < K49) ? rb[((size_t)g * K49 + q) * K49 + kcol] : 0.f;
      float v = (acc[r] + bias) * 0.125f;          // (S + rel_bias) * dh^-0.5
      sv[ct][r] = (kcol < K49) ? v : -1e30f;       // mask pad keys
    }
  }
  // ---- softmax over keys (row q lives in the 16 lanes sharing kq) ----
#pragma unroll
  for (int r = 0; r < 4; ++r) {
    float m = fmaxf(fmaxf(sv[0][r], sv[1][r]), fmaxf(sv[2][r], sv[3][r]));
#pragma unroll
    for (int d = 1; d < 16; d <<= 1) m = fmaxf(m, __shfl_xor(m, d));
    float e0 = __expf(sv[0][r] - m), e1 = __expf(sv[1][r] - m);
    float e2 = __expf(sv[2][r] - m), e3 = __expf(sv[3][r] - m);
    float s = e0 + e1 + e2 + e3;
#pragma unroll
    for (int d = 1; d < 16; d <<= 1) s += __shfl_xor(s, d);
    float inv = 1.0f / s;
    int q = wid * 16 + kq * 4 + r;
    Ps[q * 72 +  0 + l15] = __float2bfloat16(e0 * inv);
    Ps[q * 72 + 16 + l15] = __float2bfloat16(e1 * inv);
    Ps[q * 72 + 32 + l15] = __float2bfloat16(e2 * inv);
    Ps[q * 72 + 48 + l15] = __float2bfloat16(e3 * inv);
  }
  __syncthreads();
  // ---- O = P V, swapped operands: D[row=channel(kq*4+r)][col=q(l15)] ----
  bf16x8 ap[2];
#pragma unroll
  for (int kk = 0; kk < 2; ++kk)
    ap[kk] = *(const bf16x8*)&Ps[(wid * 16 + l15) * 72 + kk * 32 + kq * 8];
  f32x4 accO[4] = {};
#pragma unroll
  for (int ct = 0; ct < 4; ++ct)
#pragma unroll
    for (int kk = 0; kk < 2; ++kk) {
      bf16x8 bv = *(const bf16x8*)&Vt[(ct * 16 + l15) * 72 + kk * 32 + kq * 8];
      accO[ct] = __builtin_amdgcn_mfma_f32_16x16x32_bf16(bv, ap[kk], accO[ct], 0, 0, 0);
    }
  int q = wid * 16 + l15;
  if (q < K49) {
    int ph = q / 7, pw = q - ph * 7;
    bf16* dst = outa + (nb + (sh * 7 + ph) * WIM + sw * 7 + pw) * HD + g * 64 + kq * 4;
#pragma unroll
    for (int ct = 0; ct < 4; ++ct) {
      union { unsigned long long u; unsigned short h[4]; } pk;
#pragma unroll
      for (int r = 0; r < 4; ++r) {
        bf16 hh = __float2bfloat16(accO[ct][r]);
        pk.h[r] = *(unsigned short*)&hh;
      }
      *(unsigned long long*)(dst + ct * 16) = pk.u;
    }
  }
}

// ---------------- launch ----------------
extern "C" void kernel_launch(void* const* d_in, const int* in_sizes, int n_in,
                              void* d_out, int out_size, void* d_ws, size_t ws_size,
                              hipStream_t stream) {
  (void)in_sizes; (void)n_in; (void)out_size;
  const float* x     = (const float*)d_in[0];
  // d_in[1] = mask: all-False with zero padding (56 % 7 == 0) -> no-op, skipped
  const float* wqkv  = (const float*)d_in[2];
  const float* wproj = (const float*)d_in[3];
  const float* bproj = (const float*)d_in[4];
  const float* rb    = (const float*)d_in[5];
  // d_in[6], d_in[7] = H, W (56, 56) constants

  // workspace layout (207,618,048 bytes total)
  char* ws = (char*)d_ws;
  bf16* x_bf    = (bf16*)(ws);              // 51,380,224 B ; reused as attnout after GEMM1
  bf16* wqkv_t  = (bf16*)(ws + 51380224);   //  1,572,864 B
  bf16* wproj_t = (bf16*)(ws + 52953088);   //    524,288 B
  bf16* qkv     = (bf16*)(ws + 53477376);   // 154,140,672 B
  bf16* attno   = x_bf;
  float* out    = (float*)d_out;
  if (ws_size < 207618048) return;  // fail visibly rather than corrupt

  cvt_x_kernel<<<dim3(12544), 256, 0, stream>>>(x, x_bf);                       // 50176*512/8/256
  cvt_transpose_kernel<<<dim3(3072), 256, 0, stream>>>(wqkv, wqkv_t, 512, 1536);
  cvt_transpose_kernel<<<dim3(1024), 256, 0, stream>>>(wproj, wproj_t, 512, 512);
  // GEMM1: 196 M-tiles x 6 N-tiles = 1176 blocks (1176 % 8 == 0)
  gemm8p_kernel<1536, true, false><<<dim3(1176), 512, 0, stream>>>(
      x_bf, wqkv_t, (void*)qkv, nullptr, 6);
  attn_win_kernel<<<dim3(64, NHEAD, B_), 256, 0, stream>>>(qkv, rb, attno);
  // GEMM2: 196 x 2 = 392 blocks (392 % 8 == 0)
  gemm8p_kernel<512, false, true><<<dim3(392), 512, 0, stream>>>(
      attno, wproj_t, (void*)out, bproj, 2);
}

// Round 9
// 255.241 us; speedup vs baseline: 1.1417x; 1.0003x over previous
//
#include <hip/hip_runtime.h>
#include <hip/hip_bf16.h>

using bf16 = __hip_bfloat16;
using bf16x8 = __attribute__((ext_vector_type(8))) short;   // 8 bf16 = 4 VGPRs (MFMA A/B frag)
using f32x4  = __attribute__((ext_vector_type(4))) float;   // MFMA C/D frag (native vector)

#define B_    16
#define HIM   56
#define WIM   56
#define HD    512
#define NHEAD 8
#define DH    64
#define NTOK  (HIM*WIM)      // 3136
#define M_    (B_*NTOK)      // 50176
#define K49   49

// ---- async global->LDS, 16B per lane; LDS dest = wave-uniform base (+lane*16 by HW) ----
__device__ __forceinline__ void gload_lds16(const void* g, void* l) {
  __builtin_amdgcn_global_load_lds(
      (__attribute__((address_space(1))) const void*)g,
      (__attribute__((address_space(3))) void*)l, 16, 0, 0);
}

// ---------------- kernel: fp32 -> bf16 convert (vectorized, 8 elems/thread) ----------------
__global__ __launch_bounds__(256) void cvt_x_kernel(const float* __restrict__ in,
                                                    bf16* __restrict__ out) {
  size_t i = ((size_t)blockIdx.x * 256 + threadIdx.x) * 8;
  float4 a = *(const float4*)(in + i);
  float4 b = *(const float4*)(in + i + 4);
  union { uint4 v; bf16 h[8]; } o;
  o.h[0] = __float2bfloat16(a.x); o.h[1] = __float2bfloat16(a.y);
  o.h[2] = __float2bfloat16(a.z); o.h[3] = __float2bfloat16(a.w);
  o.h[4] = __float2bfloat16(b.x); o.h[5] = __float2bfloat16(b.y);
  o.h[6] = __float2bfloat16(b.z); o.h[7] = __float2bfloat16(b.w);
  *(uint4*)(out + i) = o.v;
}

// ---------------- kernel: W (K x N) -> Wt (N x K) bf16 ----------------
__global__ __launch_bounds__(256) void cvt_transpose_kernel(const float* __restrict__ in,
                                                            bf16* __restrict__ out,
                                                            int K, int N) {
  int idx = blockIdx.x * 256 + threadIdx.x;   // grid covers K*N exactly
  int k = idx / N, n = idx - k * N;
  out[(size_t)n * K + k] = __float2bfloat16(in[idx]);
}

// ============================================================================
// 256x256-tile GEMM with SHADOW-PHASED kslice loop.
// 512 threads = 8 waves (2M x 4N, wave tile 128x64). BK=32, 4-slot LDS ring.
// Per kslice j: { read af(j) x8 ; stage A(j+3) ; BARRIER ;
//                 16 MFMA (af x bf[0,1]) ; stage B(j+3) ;
//                 16 MFMA (af x bf[2,3]) ;
//                 PRE-READ bf(j+1) x4   <- in the barrier shadow: overlaps
//                 vmcnt(4) ; BARRIER }     other waves' MFMA tail
// B-frags double-buffered in registers (bfA/bfB by j parity) so each MFMA
// phase starts with B operands already resident; A-frags read at phase top.
// Gate algebra: end-of-(j-1) vmcnt(4) = all loads except {A(j+2),B(j+2)}
// landed => B(j+1) landed => tail pre-read of bf(j+1) and af(j+1) safe.
// Prologue vmcnt(4) proves A0,B0,A1,B1. Tail gates 4,0,0,0. Never a mid-loop
// drain-to-0 before the last 3 kslices.
// WAR on ring slot (j-1) (overwritten by stage(j+3)): last reads of slot j-1
// are af at P1(j-1) top and bf at tail of (j-2), both before end-of-(j-1)
// barrier, which precedes any wave's stage(j+3) issue. SAFE.
// XOR swizzle slot^((row>>1)&3) (rounds 1-7: SQ_LDS_BANK_CONFLICT == 0).
// mfma(b,a) operand swap -> packed 8B/16B epilogue NT stores (WRITE ideal).
// ============================================================================
template<int N, bool OUT_BF16, bool BIAS>
__global__ __launch_bounds__(512, 2) void gemm8p_kernel(
    const bf16* __restrict__ A,    // M x 512 row-major
    const bf16* __restrict__ Bt,   // N x 512 row-major
    void* __restrict__ Cp,
    const float* __restrict__ bias,
    int NBX)
{
  constexpr int K = 512;
  __shared__ alignas(16) bf16 lds[2][4][256 * 32];   // [A/B][slot][rr*32+col] = 128 KiB
  const int tid  = threadIdx.x;
  const int lane = tid & 63, wid = tid >> 6;          // 8 waves
  const int l15  = lane & 15, kq = lane >> 4;
  const int wm   = wid >> 2,  wn = wid & 3;           // 2M x 4N
  const int cpx = gridDim.x >> 3;                     // XCD swizzle (grid % 8 == 0)
  const int wg  = (blockIdx.x & 7) * cpx + (blockIdx.x >> 3);
  const int by  = wg / NBX, bx = wg - by * NBX;
  const long arow0 = (long)by * 256;
  const long bcol0 = (long)bx * 256;

  // stage half (A or B) of kslice j: 256x32 = 16KB, 2 gload_lds per thread
  auto stageHalf = [&](int ab, int j) {
    const bf16* g = (ab ? Bt + bcol0 * K : A + arow0 * K) + j * 32;
    bf16* lb = &lds[ab][j & 3][0];
#pragma unroll
    for (int c = 0; c < 2; ++c) {
      int s   = c * 512 + tid;
      int row = s >> 2, sl = s & 3;
      int gs  = sl ^ ((row >> 1) & 3);
      gload_lds16((const char*)(g + (long)row * K) + gs * 16,
                  lb + (c * 512 + wid * 64) * 8);
    }
  };
  auto rdA = [&](int slot, int mt) -> bf16x8 {
    int rr = wm * 128 + mt * 16 + l15;
    return *(const bf16x8*)&lds[0][slot][rr * 32 + ((kq ^ ((rr >> 1) & 3)) << 3)];
  };
  auto rdB = [&](int slot, int nt) -> bf16x8 {
    int rr = wn * 64 + nt * 16 + l15;
    return *(const bf16x8*)&lds[1][slot][rr * 32 + ((kq ^ ((rr >> 1) & 3)) << 3)];
  };

  f32x4 acc[8][4] = {};
  bf16x8 af[8], bfA[4], bfB[4];

  // prologue: stage kslices 0,1,2; prove {A0,B0,A1,B1}; pre-read bf(0)
  stageHalf(0, 0); stageHalf(1, 0);
  stageHalf(0, 1); stageHalf(1, 1);
  stageHalf(0, 2); stageHalf(1, 2);
  asm volatile("s_waitcnt vmcnt(4)" ::: "memory");
  __builtin_amdgcn_s_barrier();
#pragma unroll
  for (int nt = 0; nt < 4; ++nt) bfA[nt] = rdB(0, nt);

#define KS(SLOT, NSLOT, BFC, BFN, JST, DOST, PRE, VMSTR) {                    \
    _Pragma("unroll")                                                         \
    for (int mt = 0; mt < 8; ++mt) af[mt] = rdA(SLOT, mt);                    \
    if (DOST) stageHalf(0, JST);                                              \
    __builtin_amdgcn_s_barrier();                                             \
    __builtin_amdgcn_s_setprio(1);                                            \
    _Pragma("unroll")                                                         \
    for (int mt = 0; mt < 8; ++mt) {                                          \
      acc[mt][0] = __builtin_amdgcn_mfma_f32_16x16x32_bf16(BFC[0], af[mt],    \
                                                           acc[mt][0], 0,0,0);\
      acc[mt][1] = __builtin_amdgcn_mfma_f32_16x16x32_bf16(BFC[1], af[mt],    \
                                                           acc[mt][1], 0,0,0);\
    }                                                                         \
    __builtin_amdgcn_s_setprio(0);                                            \
    if (DOST) stageHalf(1, JST);                                              \
    __builtin_amdgcn_s_setprio(1);                                            \
    _Pragma("unroll")                                                         \
    for (int mt = 0; mt < 8; ++mt) {                                          \
      acc[mt][2] = __builtin_amdgcn_mfma_f32_16x16x32_bf16(BFC[2], af[mt],    \
                                                           acc[mt][2], 0,0,0);\
      acc[mt][3] = __builtin_amdgcn_mfma_f32_16x16x32_bf16(BFC[3], af[mt],    \
                                                           acc[mt][3], 0,0,0);\
    }                                                                         \
    __builtin_amdgcn_s_setprio(0);                                            \
    if (PRE) {                                                                \
      _Pragma("unroll")                                                       \
      for (int nt = 0; nt < 4; ++nt) BFN[nt] = rdB(NSLOT, nt);                \
    }                                                                         \
    asm volatile("s_waitcnt vmcnt(" VMSTR ")" ::: "memory");                  \
    __builtin_amdgcn_s_barrier();                                             \
  }

  // steady state: kslices 0..11 (slot/parity compile-time via unroll-4 group)
#pragma unroll 1
  for (int jo = 0; jo < 12; jo += 4) {
    KS(0, 1, bfA, bfB, jo + 3, 1, 1, "4");
    KS(1, 2, bfB, bfA, jo + 4, 1, 1, "4");
    KS(2, 3, bfA, bfB, jo + 5, 1, 1, "4");
    KS(3, 0, bfB, bfA, jo + 6, 1, 1, "4");
  }
  // tail: j = 12 (stages 15), 13, 14, 15
  KS(0, 1, bfA, bfB, 15, 1, 1, "4");
  KS(1, 2, bfB, bfA, 0,  0, 1, "0");
  KS(2, 3, bfA, bfB, 0,  0, 1, "0");
  KS(3, 0, bfB, bfA, 0,  0, 0, "0");
#undef KS

  // epilogue: lane holds rows crow0+mt*16+l15, cols ccol0+nt*16+kq*4+{0..3}
  const long crow0 = arow0 + wm * 128;
  const long ccol0 = bcol0 + wn * 64 + kq * 4;
#pragma unroll
  for (int mt = 0; mt < 8; ++mt) {
    long row = crow0 + mt * 16 + l15;
#pragma unroll
    for (int nt = 0; nt < 4; ++nt) {
      long col = ccol0 + nt * 16;
      if (OUT_BF16) {
        union { unsigned long long u; unsigned short h[4]; } pk;
#pragma unroll
        for (int r = 0; r < 4; ++r) {
          bf16 hh = __float2bfloat16(acc[mt][nt][r]);
          pk.h[r] = *(unsigned short*)&hh;
        }
        __builtin_nontemporal_store(pk.u,
            (unsigned long long*)((bf16*)Cp + row * N + col));
      } else {
        f32x4 o = acc[mt][nt];
        if (BIAS) {
          o[0] += bias[col];     o[1] += bias[col + 1];
          o[2] += bias[col + 2]; o[3] += bias[col + 3];
        }
        __builtin_nontemporal_store(o, (f32x4*)((float*)Cp + row * N + col));
      }
    }
  }
}

// ---------------- kernel: windowed attention, one WG per (b, window p, head g) ------------
// round-5 v1 + PV operand swap: mfma(bv, ap) -> lane holds 4 CONSECUTIVE output
// channels of one token (fragments are symmetric, identical LDS reads) ->
// 4 x 8B packed stores instead of 16 x 2B scatters.
__global__ __launch_bounds__(256) void attn_win_kernel(
    const bf16* __restrict__ qkv, const float* __restrict__ rb, bf16* __restrict__ outa)
{
  __shared__ alignas(16) bf16 Qs[64 * 72];  // [token][chan], stride 72 (144B -> 2-way free)
  __shared__ alignas(16) bf16 Ks[64 * 72];
  __shared__ alignas(16) bf16 Vt[64 * 72];  // transposed: [chan][token]
  __shared__ alignas(16) bf16 Ps[64 * 72];  // probabilities [q][k]
  const int tid = threadIdx.x, lane = tid & 63, wid = tid >> 6;
  const int p = blockIdx.x, g = blockIdx.y, b = blockIdx.z;
  const int sh = p >> 3, sw = p & 7;
  const size_t nb = (size_t)b * NTOK;
  const int c8 = (tid & 7) * 8;

  // stage Q,K row-major + V transposed; zero-fill pad tokens 49..63
#pragma unroll
  for (int it = 0; it < 2; ++it) {
    int t = (tid >> 3) + it * 32;
    uint4 vq = {0, 0, 0, 0}, vk = vq, vv = vq;
    if (t < K49) {
      int ph = t / 7, pw = t - ph * 7;
      int n = (sh * 7 + ph) * WIM + sw * 7 + pw;
      const bf16* src = qkv + (nb + n) * 1536 + g * 64 + c8;
      vq = *(const uint4*)(src);
      vk = *(const uint4*)(src + 512);
      vv = *(const uint4*)(src + 1024);
    }
    *(uint4*)&Qs[t * 72 + c8] = vq;
    *(uint4*)&Ks[t * 72 + c8] = vk;
    union { uint4 u; unsigned short s[8]; } uv; uv.u = vv;
    unsigned short* vt16 = (unsigned short*)Vt;
#pragma unroll
    for (int e = 0; e < 8; ++e) vt16[(c8 + e) * 72 + t] = uv.s[e];
  }
  __syncthreads();

  const int l15 = lane & 15, kq = lane >> 4;
  // ---- S = Q K^T (wave w owns q rows 16w..16w+15; 4 col tiles) ----
  bf16x8 aq[2];
#pragma unroll
  for (int kk = 0; kk < 2; ++kk)
    aq[kk] = *(const bf16x8*)&Qs[(wid * 16 + l15) * 72 + kk * 32 + kq * 8];
  float sv[4][4];   // [ct][r]
#pragma unroll
  for (int ct = 0; ct < 4; ++ct) {
    f32x4 acc = {0.f, 0.f, 0.f, 0.f};
#pragma unroll
    for (int kk = 0; kk < 2; ++kk) {
      bf16x8 bk = *(const bf16x8*)&Ks[(ct * 16 + l15) * 72 + kk * 32 + kq * 8];
      acc = __builtin_amdgcn_mfma_f32_16x16x32_bf16(aq[kk], bk, acc, 0, 0, 0);
    }
    int kcol = ct * 16 + l15;
#pragma unroll
    for (int r = 0; r < 4; ++r) {
      int q = wid * 16 + kq * 4 + r;
      float bias = (q < K49 && kcol < K49) ? rb[((size_t)g * K49 + q) * K49 + kcol] : 0.f;
      float v = (acc[r] + bias) * 0.125f;          // (S + rel_bias) * dh^-0.5
      sv[ct][r] = (kcol < K49) ? v : -1e30f;       // mask pad keys
    }
  }
  // ---- softmax over keys (row q lives in the 16 lanes sharing kq) ----
#pragma unroll
  for (int r = 0; r < 4; ++r) {
    float m = fmaxf(fmaxf(sv[0][r], sv[1][r]), fmaxf(sv[2][r], sv[3][r]));
#pragma unroll
    for (int d = 1; d < 16; d <<= 1) m = fmaxf(m, __shfl_xor(m, d));
    float e0 = __expf(sv[0][r] - m), e1 = __expf(sv[1][r] - m);
    float e2 = __expf(sv[2][r] - m), e3 = __expf(sv[3][r] - m);
    float s = e0 + e1 + e2 + e3;
#pragma unroll
    for (int d = 1; d < 16; d <<= 1) s += __shfl_xor(s, d);
    float inv = 1.0f / s;
    int q = wid * 16 + kq * 4 + r;
    Ps[q * 72 +  0 + l15] = __float2bfloat16(e0 * inv);
    Ps[q * 72 + 16 + l15] = __float2bfloat16(e1 * inv);
    Ps[q * 72 + 32 + l15] = __float2bfloat16(e2 * inv);
    Ps[q * 72 + 48 + l15] = __float2bfloat16(e3 * inv);
  }
  __syncthreads();
  // ---- O = P V, swapped operands: D[row=channel(kq*4+r)][col=q(l15)] ----
  bf16x8 ap[2];
#pragma unroll
  for (int kk = 0; kk < 2; ++kk)
    ap[kk] = *(const bf16x8*)&Ps[(wid * 16 + l15) * 72 + kk * 32 + kq * 8];
  f32x4 accO[4] = {};
#pragma unroll
  for (int ct = 0; ct < 4; ++ct)
#pragma unroll
    for (int kk = 0; kk < 2; ++kk) {
      bf16x8 bv = *(const bf16x8*)&Vt[(ct * 16 + l15) * 72 + kk * 32 + kq * 8];
      accO[ct] = __builtin_amdgcn_mfma_f32_16x16x32_bf16(bv, ap[kk], accO[ct], 0, 0, 0);
    }
  int q = wid * 16 + l15;
  if (q < K49) {
    int ph = q / 7, pw = q - ph * 7;
    bf16* dst = outa + (nb + (sh * 7 + ph) * WIM + sw * 7 + pw) * HD + g * 64 + kq * 4;
#pragma unroll
    for (int ct = 0; ct < 4; ++ct) {
      union { unsigned long long u; unsigned short h[4]; } pk;
#pragma unroll
      for (int r = 0; r < 4; ++r) {
        bf16 hh = __float2bfloat16(accO[ct][r]);
        pk.h[r] = *(unsigned short*)&hh;
      }
      *(unsigned long long*)(dst + ct * 16) = pk.u;
    }
  }
}

// ---------------- launch ----------------
extern "C" void kernel_launch(void* const* d_in, const int* in_sizes, int n_in,
                              void* d_out, int out_size, void* d_ws, size_t ws_size,
                              hipStream_t stream) {
  (void)in_sizes; (void)n_in; (void)out_size;
  const float* x     = (const float*)d_in[0];
  // d_in[1] = mask: all-False with zero padding (56 % 7 == 0) -> no-op, skipped
  const float* wqkv  = (const float*)d_in[2];
  const float* wproj = (const float*)d_in[3];
  const float* bproj = (const float*)d_in[4];
  const float* rb    = (const float*)d_in[5];
  // d_in[6], d_in[7] = H, W (56, 56) constants

  // workspace layout (207,618,048 bytes total)
  char* ws = (char*)d_ws;
  bf16* x_bf    = (bf16*)(ws);              // 51,380,224 B ; reused as attnout after GEMM1
  bf16* wqkv_t  = (bf16*)(ws + 51380224);   //  1,572,864 B
  bf16* wproj_t = (bf16*)(ws + 52953088);   //    524,288 B
  bf16* qkv     = (bf16*)(ws + 53477376);   // 154,140,672 B
  bf16* attno   = x_bf;
  float* out    = (float*)d_out;
  if (ws_size < 207618048) return;  // fail visibly rather than corrupt

  cvt_x_kernel<<<dim3(12544), 256, 0, stream>>>(x, x_bf);                       // 50176*512/8/256
  cvt_transpose_kernel<<<dim3(3072), 256, 0, stream>>>(wqkv, wqkv_t, 512, 1536);
  cvt_transpose_kernel<<<dim3(1024), 256, 0, stream>>>(wproj, wproj_t, 512, 512);
  // GEMM1: 196 M-tiles x 6 N-tiles = 1176 blocks (1176 % 8 == 0)
  gemm8p_kernel<1536, true, false><<<dim3(1176), 512, 0, stream>>>(
      x_bf, wqkv_t, (void*)qkv, nullptr, 6);
  attn_win_kernel<<<dim3(64, NHEAD, B_), 256, 0, stream>>>(qkv, rb, attno);
  // GEMM2: 196 x 2 = 392 blocks (392 % 8 == 0)
  gemm8p_kernel<512, false, true><<<dim3(392), 512, 0, stream>>>(
      attno, wproj_t, (void*)out, bproj, 2);
}